// Round 17
// baseline (576.629 us; speedup 1.0000x reference)
//
#include <hip/hip_runtime.h>
#include <hip/hip_bf16.h>

typedef unsigned short u16;
typedef unsigned int u32;
typedef short bf16x8 __attribute__((ext_vector_type(8)));
typedef float f32x4 __attribute__((ext_vector_type(4)));
typedef u16 u16x8 __attribute__((ext_vector_type(8)));
typedef u16 u16x4 __attribute__((ext_vector_type(4)));
typedef u32 u32x2 __attribute__((ext_vector_type(2)));
typedef u32 u32x4 __attribute__((ext_vector_type(4)));

// ws layout (u16 elements)
#define WQ_ 0
#define WK_ 262144
#define WV_ 524288
#define WO_ 786432
#define QP_ 1048576
#define KP_ (QP_ + 4194304)
#define VT_ (KP_ + 4194304)
#define OW_ (VT_ + 4194304)

#define C1F 0.18033688011112042f  // log2(e)/8

__device__ __forceinline__ u16 f2bf(float f) {
  unsigned x = __float_as_uint(f);
  return (u16)((x + 0x7fffu + ((x >> 16) & 1u)) >> 16);
}

__device__ __forceinline__ u32 packbf2(float a, float b) {
  u32 lo = (u32)__bfloat16_as_ushort(__float2bfloat16(a));
  u32 hi = (u32)__bfloat16_as_ushort(__float2bfloat16(b));
  return lo | (hi << 16);
}

__device__ __forceinline__ void async16(const void* g, void* l) {
  __builtin_amdgcn_global_load_lds(
      (const __attribute__((address_space(1))) unsigned int*)g,
      (__attribute__((address_space(3))) unsigned int*)l, 16, 0, 0);
}

// ---------------- f32 -> bf16 conversion of the four weight matrices -------
__global__ void convert_w(const float* __restrict__ Wq, const float* __restrict__ Wk,
                          const float* __restrict__ Wv, const float* __restrict__ Wo,
                          u16* __restrict__ ws) {
  int seg = blockIdx.y;
  const float* src = (seg == 0) ? Wq : (seg == 1) ? Wk : (seg == 2) ? Wv : Wo;
  u16* dst = ws + seg * 262144;
  int i = (blockIdx.x * 256 + threadIdx.x) * 8;
  float4 a = *(const float4*)(src + i);
  float4 b = *(const float4*)(src + i + 4);
  u16x8 o;
  o[0] = f2bf(a.x); o[1] = f2bf(a.y); o[2] = f2bf(a.z); o[3] = f2bf(a.w);
  o[4] = f2bf(b.x); o[5] = f2bf(b.y); o[6] = f2bf(b.z); o[7] = f2bf(b.w);
  *(u16x8*)(dst + i) = o;
}

// ---------------- NT GEMM: C[r,c] = sum_d A[r,d]*W[c,d] + bias[c] ----------
// MODE 0: MT=128. A = f32 input (Qi/Ki/Vi by z), reg-convert staging.
// MODE 1: MT=64 (grid 512 -> 2 blocks/CU). A = OW bf16, W = Wo; f32 out+bias.
template <int MODE>
__global__ __launch_bounds__(256, 3) void gemm_nt(
    const float* __restrict__ A0, const float* __restrict__ A1,
    const float* __restrict__ A2, u16* __restrict__ ws,
    const float* __restrict__ bias0, const float* __restrict__ bias1,
    const float* __restrict__ bias2, float* __restrict__ outF) {
  constexpr int MT = (MODE == 0) ? 128 : 64;
  constexpr int RB = MT / 32;
  const int tid = threadIdx.x, lane = tid & 63, wave = tid >> 6;
  const int wm = wave >> 1, wn = wave & 1;
  const int z = blockIdx.z;
  const float* Af = (z == 0) ? A0 : (z == 1) ? A1 : A2;
  const u16* W = ws + (MODE == 0 ? z * 262144 : (int)WO_);
  const u16* Ab = ws + OW_;
  const float* bias = (z == 0) ? bias0 : (z == 1) ? bias1 : bias2;
  const int bm0 = blockIdx.y * MT, bn0 = blockIdx.x * 128;

  __shared__ u16 At[MT * 64];
  __shared__ u16 Bt[8192];

  f32x4 acc[RB][4];
#pragma unroll
  for (int i = 0; i < RB; ++i)
#pragma unroll
    for (int j = 0; j < 4; ++j) acc[i][j] = (f32x4){0.f, 0.f, 0.f, 0.f};

  const int grp16 = (lane >> 4) * 16;

  for (int kt = 0; kt < 8; ++kt) {
    __syncthreads();
#pragma unroll
    for (int c = 0; c < 4; ++c) {
      int o = wave * 4096 + c * 1024 + lane * 16;
      int row = o >> 7;
      int colb = (o & 127) ^ ((row & 7) << 4);
      async16((const char*)W + (size_t)(bn0 + row) * 1024 + kt * 128 + colb,
              (char*)Bt + wave * 4096 + c * 1024);
    }
    if (MODE == 1) {
#pragma unroll
      for (int c = 0; c < RB; ++c) {
        int o = wave * (MT * 32) + c * 1024 + lane * 16;
        int row = o >> 7;
        int colb = (o & 127) ^ ((row & 7) << 4);
        async16((const char*)Ab + (size_t)(bm0 + row) * 1024 + kt * 128 + colb,
                (char*)At + wave * (MT * 32) + c * 1024);
      }
    }
    if (MODE == 0) {
#pragma unroll
      for (int i = 0; i < 4; ++i) {
        int c = tid + 256 * i;
        int row = c >> 3, fc = (c & 7) * 8;
        const float* s = Af + (size_t)(bm0 + row) * 512 + kt * 64 + fc;
        f32x4 x0 = *(const f32x4*)s;
        f32x4 x1 = *(const f32x4*)(s + 4);
        u16x8 p;
        p[0] = __bfloat16_as_ushort(__float2bfloat16(x0[0]));
        p[1] = __bfloat16_as_ushort(__float2bfloat16(x0[1]));
        p[2] = __bfloat16_as_ushort(__float2bfloat16(x0[2]));
        p[3] = __bfloat16_as_ushort(__float2bfloat16(x0[3]));
        p[4] = __bfloat16_as_ushort(__float2bfloat16(x1[0]));
        p[5] = __bfloat16_as_ushort(__float2bfloat16(x1[1]));
        p[6] = __bfloat16_as_ushort(__float2bfloat16(x1[2]));
        p[7] = __bfloat16_as_ushort(__float2bfloat16(x1[3]));
        int db = row * 128 + ((fc * 2) ^ ((row & 7) << 4));
        *(u16x8*)((char*)At + db) = p;
      }
    }
    __syncthreads();
    bf16x8 af[RB][2], bfr[4][2];
#pragma unroll
    for (int rb = 0; rb < RB; ++rb) {
      int row = wm * (MT / 2) + rb * 16 + (lane & 15);
      const char* base = (const char*)At + row * 128;
      int sw = (row & 7) << 4;
      af[rb][0] = *(const bf16x8*)(base + (grp16 ^ sw));
      af[rb][1] = *(const bf16x8*)(base + ((64 + grp16) ^ sw));
    }
#pragma unroll
    for (int cb = 0; cb < 4; ++cb) {
      int row = wn * 64 + cb * 16 + (lane & 15);
      const char* base = (const char*)Bt + row * 128;
      int sw = (row & 7) << 4;
      bfr[cb][0] = *(const bf16x8*)(base + (grp16 ^ sw));
      bfr[cb][1] = *(const bf16x8*)(base + ((64 + grp16) ^ sw));
    }
#pragma unroll
    for (int rb = 0; rb < RB; ++rb)
#pragma unroll
      for (int cb = 0; cb < 4; ++cb) {
        acc[rb][cb] = __builtin_amdgcn_mfma_f32_16x16x32_bf16(af[rb][0], bfr[cb][0],
                                                              acc[rb][cb], 0, 0, 0);
        acc[rb][cb] = __builtin_amdgcn_mfma_f32_16x16x32_bf16(af[rb][1], bfr[cb][1],
                                                              acc[rb][cb], 0, 0, 0);
      }
  }

#pragma unroll
  for (int rb = 0; rb < RB; ++rb) {
#pragma unroll
    for (int cb = 0; cb < 4; ++cb) {
      int col = bn0 + wn * 64 + cb * 16 + (lane & 15);
      float bvl = bias[col];
#pragma unroll
      for (int r = 0; r < 4; ++r) {
        int rr = bm0 + wm * (MT / 2) + rb * 16 + (lane >> 4) * 4 + r;
        float v = acc[rb][cb][r] + bvl;
        if (MODE == 1) {
          outF[(size_t)rr * 512 + col] = v;
        } else {
          int b = rr >> 11, q = rr & 2047, hh = col >> 6, dd = col & 63;
          int bh = (b << 3) | hh;
          if (z == 0) {
            ws[QP_ + (size_t)(bh * 2048 + q) * 64 + dd] = f2bf(v * C1F);
          } else if (z == 1) {
            ws[KP_ + (size_t)(bh * 2048 + q) * 64 + dd] = f2bf(v);
          } else {
            ws[VT_ + (size_t)bh * 131072 + (size_t)dd * 2048 + q] = f2bf(v);
          }
        }
      }
    }
  }
}

// ---------------- fused attention, k-partitioned, barrier-free -------------
// grid (64 qtiles of 32, 32 = h*4+b), 256 thr = 4 waves. Wave w owns k-slice
// [t*128 + w*32, +32) of each 128-k tile. K/V staged via REGISTER double
// buffer (coalesced dwordx4 loads issued one iteration early, ds_write to
// WAVE-PRIVATE LDS at the top of the next iteration) -> full-body latency
// cover, compiler-managed waits, ZERO barriers in the main loops.
// Cross-wave Z-combine and O-reduction epilogues as in R14 (verified).
__global__ __launch_bounds__(256, 4) void attn_kernel(u16* __restrict__ ws,
                                                      const float* __restrict__ Mg,
                                                      const float* __restrict__ la,
                                                      float* __restrict__ attnOut) {
  const int tid = threadIdx.x, lane = tid & 63, wv = tid >> 6;
  const int colLane = lane & 15, grp = lane >> 4;
  const int yb = blockIdx.y, h = yb >> 2, b = yb & 3, bh = b * 8 + h;
  const int q0 = blockIdx.x * 32;
  const u16* Qp = ws + QP_ + (size_t)bh * 131072;
  const char* Kg = (const char*)(ws + KP_ + (size_t)bh * 131072);
  const char* Vg = (const char*)(ws + VT_ + (size_t)bh * 131072);
  const float* Mh = Mg + (size_t)h * 4194304;
  float alpha = 1.f / (1.f + __expf(-la[h]));
  float oma = 1.f - alpha;

  // pool: 4 waves x (Kw 4KB + Vw 4KB) = 32KB, + Zbuf 512B. O-reduce reuses 32KB.
  __shared__ u16 pool[16640];
  char* Kw = (char*)pool + wv * 8192;  // [32k][64d] bf16, rows 128B, xor-swz
  char* Vw = Kw + 4096;                // [64d][32k] bf16, rows 64B, slot-swz
  float* Zbuf = (float*)((char*)pool + 32768);

  // Q fragments (B-operand): lane holds Q[q=qb*16+colLane][d=dh*32+grp*8+j]
  bf16x8 qf[2][2];
#pragma unroll
  for (int qb = 0; qb < 2; ++qb)
#pragma unroll
    for (int dh = 0; dh < 2; ++dh)
      qf[qb][dh] = *(const bf16x8*)(Qp + (size_t)(q0 + qb * 16 + colLane) * 64 +
                                    dh * 32 + grp * 8);

  // coalesced register loads (linear global), swizzled private ds_write
  auto loadK = [&](int t, u32x4 kr[4]) {
#pragma unroll
    for (int c = 0; c < 4; ++c) {
      int o = c * 1024 + lane * 16;
      int row = o >> 7;
      kr[c] = *(const u32x4*)(Kg + (size_t)(t * 128 + wv * 32 + row) * 128 +
                              (o & 127));
    }
  };
  auto loadV = [&](int t, u32x4 vr[4]) {
#pragma unroll
    for (int c = 0; c < 4; ++c) {
      int o = c * 1024 + lane * 16;
      int d = o >> 6;
      vr[c] = *(const u32x4*)(Vg + (size_t)d * 4096 + (size_t)(t * 128 + wv * 32) * 2 +
                              (o & 63));
    }
  };
  auto writeK = [&](const u32x4 kr[4]) {
#pragma unroll
    for (int c = 0; c < 4; ++c) {
      int o = c * 1024 + lane * 16;
      int row = o >> 7;
      *(u32x4*)(Kw + row * 128 + ((o & 127) ^ ((row & 7) << 4))) = kr[c];
    }
  };
  auto writeV = [&](const u32x4 vr[4]) {
#pragma unroll
    for (int c = 0; c < 4; ++c) {
      int o = c * 1024 + lane * 16;
      int d = o >> 6;
      *(u32x4*)(Vw + d * 64 + ((o & 63) ^ ((d & 3) << 4))) = vr[c];
    }
  };
  // S^T[k=kb*16+4grp+r][q=qb*16+colLane] for this wave's 32-k slice
  auto qk = [&](float sc[2][2][4]) {
    bf16x8 kf[2][2];
#pragma unroll
    for (int kb = 0; kb < 2; ++kb) {
      int row = kb * 16 + colLane;
      int sw = (row & 7) << 4;
#pragma unroll
      for (int dh = 0; dh < 2; ++dh)
        kf[kb][dh] = *(const bf16x8*)(Kw + row * 128 + ((dh * 64 + grp * 16) ^ sw));
    }
    __builtin_amdgcn_s_setprio(1);
#pragma unroll
    for (int kb = 0; kb < 2; ++kb)
#pragma unroll
      for (int qb = 0; qb < 2; ++qb) {
        f32x4 a = (f32x4){0.f, 0.f, 0.f, 0.f};
        a = __builtin_amdgcn_mfma_f32_16x16x32_bf16(kf[kb][0], qf[qb][0], a, 0, 0, 0);
        a = __builtin_amdgcn_mfma_f32_16x16x32_bf16(kf[kb][1], qf[qb][1], a, 0, 0, 0);
#pragma unroll
        for (int r = 0; r < 4; ++r) sc[kb][qb][r] = a[r];
      }
    __builtin_amdgcn_s_setprio(0);
  };

  // ---- pass 1: Z partials (wave-private, barrier-free, reg-dbuf) ----
  u32x4 kr[4];
  loadK(0, kr);
  float zp0 = 0.f, zp1 = 0.f;
  for (int t = 0; t < 16; ++t) {
    writeK(kr);  // compiler waits vmcnt on kr regs (issued last iteration)
    if (t < 15) loadK(t + 1, kr);
    float sc[2][2][4];
    qk(sc);
#pragma unroll
    for (int kb = 0; kb < 2; ++kb)
#pragma unroll
      for (int r = 0; r < 4; ++r) {
        zp0 += exp2f(sc[kb][0][r]);
        zp1 += exp2f(sc[kb][1][r]);
      }
  }
  zp0 += __shfl_xor(zp0, 16); zp0 += __shfl_xor(zp0, 32);
  zp1 += __shfl_xor(zp1, 16); zp1 += __shfl_xor(zp1, 32);
  if (lane < 16) {
    Zbuf[wv * 32 + lane] = zp0;
    Zbuf[wv * 32 + 16 + lane] = zp1;
  }
  __syncthreads();
  float aZ[2], oZ[2];
#pragma unroll
  for (int qb = 0; qb < 2; ++qb) {
    float z = Zbuf[qb * 16 + colLane] + Zbuf[32 + qb * 16 + colLane] +
              Zbuf[64 + qb * 16 + colLane] + Zbuf[96 + qb * 16 + colLane];
    float iz = 1.f / z;
    aZ[qb] = alpha * iz;
    oZ[qb] = oma * iz;
  }

  // ---- pass 2: gate + attn write + PV (wave-private, barrier-free) ----
  f32x4 oacc[4][2];  // O^T[d-block][q-block]
#pragma unroll
  for (int db = 0; db < 4; ++db)
#pragma unroll
    for (int qb = 0; qb < 2; ++qb) oacc[db][qb] = (f32x4){0.f, 0.f, 0.f, 0.f};

  const float* Mrow[2];
  float* Arow[2];
#pragma unroll
  for (int qb = 0; qb < 2; ++qb) {
    int qg = q0 + qb * 16 + colLane;
    Mrow[qb] = Mh + (size_t)qg * 2048 + wv * 32 + grp * 4;
    Arow[qb] = attnOut + ((size_t)(bh * 2048 + qg)) * 2048 + wv * 32 + grp * 4;
  }
  // P strip overlaid in Kw (K data dead after qk): [qb][16q rows of 80B]
  char* Pb = Kw;

  u32x4 vr[4];
  loadK(0, kr);
  loadV(0, vr);
  for (int t = 0; t < 16; ++t) {
    writeK(kr);
    writeV(vr);
    if (t < 15) { loadK(t + 1, kr); loadV(t + 1, vr); }
    // M loads for this iteration (hoisted; cover under qk)
    float4 mreg[2][2];
#pragma unroll
    for (int qb = 0; qb < 2; ++qb)
#pragma unroll
      for (int kb = 0; kb < 2; ++kb)
        mreg[kb][qb] = *(const float4*)(Mrow[qb] + t * 128 + kb * 16);
    float sc[2][2][4];
    qk(sc);
    // gate, attn store (nt), P strip write
#pragma unroll
    for (int kb = 0; kb < 2; ++kb)
#pragma unroll
      for (int qb = 0; qb < 2; ++qb) {
        f32x4 uv;
        uv[0] = exp2f(sc[kb][qb][0]) * fmaf(aZ[qb], mreg[kb][qb].x, oZ[qb]);
        uv[1] = exp2f(sc[kb][qb][1]) * fmaf(aZ[qb], mreg[kb][qb].y, oZ[qb]);
        uv[2] = exp2f(sc[kb][qb][2]) * fmaf(aZ[qb], mreg[kb][qb].z, oZ[qb]);
        uv[3] = exp2f(sc[kb][qb][3]) * fmaf(aZ[qb], mreg[kb][qb].w, oZ[qb]);
        __builtin_nontemporal_store(uv, (f32x4*)(Arow[qb] + t * 128 + kb * 16));
        u32x2 pv;
        pv[0] = packbf2(uv[0], uv[1]);
        pv[1] = packbf2(uv[2], uv[3]);
        *(u32x2*)(Pb + qb * 1280 + colLane * 80 + kb * 32 + grp * 8) = pv;
      }
    // PV: B = P[q=colLane][k=8grp+j], A = V^T[d][k=8grp+j]
    bf16x8 pf[2];
#pragma unroll
    for (int qb = 0; qb < 2; ++qb)
      pf[qb] = *(const bf16x8*)(Pb + qb * 1280 + colLane * 80 + grp * 16);
    __builtin_amdgcn_s_setprio(1);
#pragma unroll
    for (int db = 0; db < 4; ++db) {
      int d = db * 16 + colLane;
      bf16x8 vf = *(const bf16x8*)(Vw + d * 64 + ((grp * 16) ^ ((d & 3) << 4)));
#pragma unroll
      for (int qb = 0; qb < 2; ++qb)
        oacc[db][qb] = __builtin_amdgcn_mfma_f32_16x16x32_bf16(vf, pf[qb],
                                                               oacc[db][qb], 0, 0, 0);
    }
    __builtin_amdgcn_s_setprio(0);
  }

  // ---- cross-wave O reduction: pool reused as f32 Obuf[4][32q][64d] ----
  __syncthreads();  // all waves done with their LDS regions
  float* Ob = (float*)pool;
#pragma unroll
  for (int db = 0; db < 4; ++db)
#pragma unroll
    for (int qb = 0; qb < 2; ++qb) {
      *(f32x4*)((char*)Ob + wv * 8192 + (qb * 16 + colLane) * 256 +
                (db * 16 + grp * 4) * 4) = oacc[db][qb];
    }
  __syncthreads();
#pragma unroll
  for (int j = 0; j < 2; ++j) {
    int idx = tid * 8 + j * 4;  // f32 index in [0, 2048)
    int q = idx >> 6, d = idx & 63;
    f32x4 s = *(const f32x4*)((char*)Ob + q * 256 + d * 4);
#pragma unroll
    for (int w = 1; w < 4; ++w) {
      f32x4 sw2 = *(const f32x4*)((char*)Ob + w * 8192 + q * 256 + d * 4);
      s[0] += sw2[0]; s[1] += sw2[1]; s[2] += sw2[2]; s[3] += sw2[3];
    }
    u16x4 ov;
    ov[0] = f2bf(s[0]); ov[1] = f2bf(s[1]); ov[2] = f2bf(s[2]); ov[3] = f2bf(s[3]);
    *(u16x4*)(ws + OW_ + (size_t)(b * 2048 + q0 + q) * 512 + h * 64 + d) = ov;
  }
}

extern "C" void kernel_launch(void* const* d_in, const int* in_sizes, int n_in,
                              void* d_out, int out_size, void* d_ws, size_t ws_size,
                              hipStream_t stream) {
  const float* Qi = (const float*)d_in[0];
  const float* Ki = (const float*)d_in[1];
  const float* Vi = (const float*)d_in[2];
  const float* M = (const float*)d_in[3];
  const float* Wq = (const float*)d_in[4];
  const float* bq = (const float*)d_in[5];
  const float* Wk = (const float*)d_in[6];
  const float* bk = (const float*)d_in[7];
  const float* Wv = (const float*)d_in[8];
  const float* bv = (const float*)d_in[9];
  const float* Wo = (const float*)d_in[10];
  const float* bo = (const float*)d_in[11];
  const float* la = (const float*)d_in[12];
  u16* ws = (u16*)d_ws;
  float* outMain = (float*)d_out;
  float* outAttn = outMain + 4194304;

  convert_w<<<dim3(128, 4), 256, 0, stream>>>(Wq, Wk, Wv, Wo, ws);
  gemm_nt<0><<<dim3(4, 64, 3), 256, 0, stream>>>(Qi, Ki, Vi, ws, bq, bk, bv, nullptr);
  attn_kernel<<<dim3(64, 32), 256, 0, stream>>>(ws, M, la, outAttn);
  gemm_nt<1><<<dim3(4, 128, 1), 256, 0, stream>>>(nullptr, nullptr, nullptr, ws, bo,
                                                  nullptr, nullptr, outMain);
}

// Round 18
// 234.598 us; speedup vs baseline: 2.4579x; 2.4579x over previous
//
#include <hip/hip_runtime.h>
#include <hip/hip_bf16.h>

typedef unsigned short u16;
typedef unsigned int u32;
typedef short bf16x8 __attribute__((ext_vector_type(8)));
typedef float f32x4 __attribute__((ext_vector_type(4)));
typedef u16 u16x8 __attribute__((ext_vector_type(8)));
typedef u32 u32x2 __attribute__((ext_vector_type(2)));

// ws layout (u16 elements)
#define WQ_ 0
#define WK_ 262144
#define WV_ 524288
#define WO_ 786432
#define QP_ 1048576
#define KP_ (QP_ + 4194304)
#define VT_ (KP_ + 4194304)
#define OW_ (VT_ + 4194304)

#define C1F 0.18033688011112042f  // log2(e)/8

__device__ __forceinline__ u16 f2bf(float f) {
  unsigned x = __float_as_uint(f);
  return (u16)((x + 0x7fffu + ((x >> 16) & 1u)) >> 16);
}

__device__ __forceinline__ u32 packbf2(float a, float b) {
  u32 lo = (u32)__bfloat16_as_ushort(__float2bfloat16(a));
  u32 hi = (u32)__bfloat16_as_ushort(__float2bfloat16(b));
  return lo | (hi << 16);
}

__device__ __forceinline__ void async16(const void* g, void* l) {
  __builtin_amdgcn_global_load_lds(
      (const __attribute__((address_space(1))) unsigned int*)g,
      (__attribute__((address_space(3))) unsigned int*)l, 16, 0, 0);
}

// ---------------- f32 -> bf16 conversion of the four weight matrices -------
__global__ void convert_w(const float* __restrict__ Wq, const float* __restrict__ Wk,
                          const float* __restrict__ Wv, const float* __restrict__ Wo,
                          u16* __restrict__ ws) {
  int seg = blockIdx.y;
  const float* src = (seg == 0) ? Wq : (seg == 1) ? Wk : (seg == 2) ? Wv : Wo;
  u16* dst = ws + seg * 262144;
  int i = (blockIdx.x * 256 + threadIdx.x) * 8;
  float4 a = *(const float4*)(src + i);
  float4 b = *(const float4*)(src + i + 4);
  u16x8 o;
  o[0] = f2bf(a.x); o[1] = f2bf(a.y); o[2] = f2bf(a.z); o[3] = f2bf(a.w);
  o[4] = f2bf(b.x); o[5] = f2bf(b.y); o[6] = f2bf(b.z); o[7] = f2bf(b.w);
  *(u16x8*)(dst + i) = o;
}

// ---------------- NT GEMM: C[r,c] = sum_d A[r,d]*W[c,d] + bias[c] ----------
// MODE 0: MT=128. A = f32 input (Qi/Ki/Vi by z), reg-convert staging.
//         epilogue: z=0 -> QP (scaled by C1F), z=1 -> KP, z=2 -> VT (V^T).
// MODE 1: MT=64 (2 blocks/CU at grid 512). A = OW bf16, W = Wo; f32 out+bias.
template <int MODE>
__global__ __launch_bounds__(256, 3) void gemm_nt(
    const float* __restrict__ A0, const float* __restrict__ A1,
    const float* __restrict__ A2, u16* __restrict__ ws,
    const float* __restrict__ bias0, const float* __restrict__ bias1,
    const float* __restrict__ bias2, float* __restrict__ outF) {
  constexpr int MT = (MODE == 0) ? 128 : 64;   // M tile
  constexpr int RB = MT / 32;                  // 16-row frags per wave
  const int tid = threadIdx.x, lane = tid & 63, wave = tid >> 6;
  const int wm = wave >> 1, wn = wave & 1;
  const int z = blockIdx.z;
  const float* Af = (z == 0) ? A0 : (z == 1) ? A1 : A2;
  const u16* W = ws + (MODE == 0 ? z * 262144 : (int)WO_);
  const u16* Ab = ws + OW_;
  const float* bias = (z == 0) ? bias0 : (z == 1) ? bias1 : bias2;
  const int bm0 = blockIdx.y * MT, bn0 = blockIdx.x * 128;

  __shared__ u16 At[MT * 64];  // MT x 64 bf16, row-xor-swizzled
  __shared__ u16 Bt[8192];     // 128 x 64 bf16

  f32x4 acc[RB][4];
#pragma unroll
  for (int i = 0; i < RB; ++i)
#pragma unroll
    for (int j = 0; j < 4; ++j) acc[i][j] = (f32x4){0.f, 0.f, 0.f, 0.f};

  const int grp16 = (lane >> 4) * 16;

  for (int kt = 0; kt < 8; ++kt) {
    __syncthreads();
#pragma unroll
    for (int c = 0; c < 4; ++c) {
      int o = wave * 4096 + c * 1024 + lane * 16;
      int row = o >> 7;
      int colb = (o & 127) ^ ((row & 7) << 4);
      async16((const char*)W + (size_t)(bn0 + row) * 1024 + kt * 128 + colb,
              (char*)Bt + wave * 4096 + c * 1024);
    }
    if (MODE == 1) {
#pragma unroll
      for (int c = 0; c < RB; ++c) {
        int o = wave * (MT * 32) + c * 1024 + lane * 16;
        int row = o >> 7;
        int colb = (o & 127) ^ ((row & 7) << 4);
        async16((const char*)Ab + (size_t)(bm0 + row) * 1024 + kt * 128 + colb,
                (char*)At + wave * (MT * 32) + c * 1024);
      }
    }
    if (MODE == 0) {
#pragma unroll
      for (int i = 0; i < 4; ++i) {
        int c = tid + 256 * i;
        int row = c >> 3, fc = (c & 7) * 8;
        const float* s = Af + (size_t)(bm0 + row) * 512 + kt * 64 + fc;
        f32x4 x0 = *(const f32x4*)s;
        f32x4 x1 = *(const f32x4*)(s + 4);
        u16x8 p;
        p[0] = __bfloat16_as_ushort(__float2bfloat16(x0[0]));
        p[1] = __bfloat16_as_ushort(__float2bfloat16(x0[1]));
        p[2] = __bfloat16_as_ushort(__float2bfloat16(x0[2]));
        p[3] = __bfloat16_as_ushort(__float2bfloat16(x0[3]));
        p[4] = __bfloat16_as_ushort(__float2bfloat16(x1[0]));
        p[5] = __bfloat16_as_ushort(__float2bfloat16(x1[1]));
        p[6] = __bfloat16_as_ushort(__float2bfloat16(x1[2]));
        p[7] = __bfloat16_as_ushort(__float2bfloat16(x1[3]));
        int db = row * 128 + ((fc * 2) ^ ((row & 7) << 4));
        *(u16x8*)((char*)At + db) = p;
      }
    }
    __syncthreads();
    bf16x8 af[RB][2], bfr[4][2];
#pragma unroll
    for (int rb = 0; rb < RB; ++rb) {
      int row = wm * (MT / 2) + rb * 16 + (lane & 15);
      const char* base = (const char*)At + row * 128;
      int sw = (row & 7) << 4;
      af[rb][0] = *(const bf16x8*)(base + (grp16 ^ sw));
      af[rb][1] = *(const bf16x8*)(base + ((64 + grp16) ^ sw));
    }
#pragma unroll
    for (int cb = 0; cb < 4; ++cb) {
      int row = wn * 64 + cb * 16 + (lane & 15);
      const char* base = (const char*)Bt + row * 128;
      int sw = (row & 7) << 4;
      bfr[cb][0] = *(const bf16x8*)(base + (grp16 ^ sw));
      bfr[cb][1] = *(const bf16x8*)(base + ((64 + grp16) ^ sw));
    }
#pragma unroll
    for (int rb = 0; rb < RB; ++rb)
#pragma unroll
      for (int cb = 0; cb < 4; ++cb) {
        acc[rb][cb] = __builtin_amdgcn_mfma_f32_16x16x32_bf16(af[rb][0], bfr[cb][0],
                                                              acc[rb][cb], 0, 0, 0);
        acc[rb][cb] = __builtin_amdgcn_mfma_f32_16x16x32_bf16(af[rb][1], bfr[cb][1],
                                                              acc[rb][cb], 0, 0, 0);
      }
  }

#pragma unroll
  for (int rb = 0; rb < RB; ++rb) {
#pragma unroll
    for (int cb = 0; cb < 4; ++cb) {
      int col = bn0 + wn * 64 + cb * 16 + (lane & 15);
      float bvl = bias[col];
#pragma unroll
      for (int r = 0; r < 4; ++r) {
        int rr = bm0 + wm * (MT / 2) + rb * 16 + (lane >> 4) * 4 + r;
        float v = acc[rb][cb][r] + bvl;
        if (MODE == 1) {
          outF[(size_t)rr * 512 + col] = v;
        } else {
          int b = rr >> 11, q = rr & 2047, hh = col >> 6, dd = col & 63;
          int bh = (b << 3) | hh;
          if (z == 0) {
            ws[QP_ + (size_t)(bh * 2048 + q) * 64 + dd] = f2bf(v * C1F);
          } else if (z == 1) {
            ws[KP_ + (size_t)(bh * 2048 + q) * 64 + dd] = f2bf(v);
          } else {
            ws[VT_ + (size_t)bh * 131072 + (size_t)dd * 2048 + q] = f2bf(v);
          }
        }
      }
    }
  }
}

// ---------------- fused attention (R12 structure) --------------------------
// grid (32 qtiles, 32 = h*4+b), 256 threads = 4 waves, each wave 16 q-rows.
// Swapped QK^T: C = S^T (row=k, col=q); Q pre-scaled by C1F.
// Pass 1: 128-k dbuf tiles (16 iters). Pass 2: 64-k K+V dbuf + Pl strip.
__global__ __launch_bounds__(256, 4) void attn_kernel(u16* __restrict__ ws,
                                                      const float* __restrict__ Mg,
                                                      const float* __restrict__ la,
                                                      float* __restrict__ attnOut) {
  const int tid = threadIdx.x, lane = tid & 63, wv = tid >> 6;
  const int colLane = lane & 15, grp = lane >> 4;
  const int yb = blockIdx.y, h = yb >> 2, b = yb & 3, bh = b * 8 + h;
  const int q0 = blockIdx.x * 64;
  const u16* Qp = ws + QP_ + (size_t)bh * 131072;
  const u16* Kp = ws + KP_ + (size_t)bh * 131072;
  const u16* Vtg = ws + VT_ + (size_t)bh * 131072;
  const float* Mh = Mg + (size_t)h * 4194304;
  float alpha = 1.f / (1.f + __expf(-la[h]));
  float oma = 1.f - alpha;

  // 40KB unified pool.
  // pass 1: two 16KB K-tiles (128k x 64d) at byte 0 / 16384.
  // pass 2: Kt dbuf @0 (2x8KB), Vt dbuf @16384 (2x8KB), Pl @32768 (8KB).
  __shared__ u16 pool[20480];

  const int grp16 = grp * 16;

  // Q fragment (B-operand): lane holds Q[q=colLane][d=grp*8+j]
  bf16x8 qa0, qa1;
  {
    const u16* qb = Qp + (size_t)(q0 + wv * 16 + colLane) * 64;
    qa0 = *(const bf16x8*)(qb + grp * 8);
    qa1 = *(const bf16x8*)(qb + 32 + grp * 8);
  }

  // ---- pass 1: Z = sum exp2(S~), 128-k tiles, 16 iterations ----
  auto stage1 = [&](int buf, int kt2) {
#pragma unroll
    for (int c = 0; c < 4; ++c) {
      int o = (c * 256 + tid) * 16;  // 0..16383
      int row = o >> 7;              // 0..127
      int colb = (o & 127) ^ ((row & 7) << 4);
      async16((const char*)Kp + kt2 * 16384 + row * 128 + colb,
              (char*)pool + buf * 16384 + o);
    }
  };
  float zp = 0.f;
  stage1(0, 0);
  __syncthreads();
  int cur = 0;
  for (int kt2 = 0; kt2 < 16; ++kt2) {
    if (kt2 < 15) stage1(cur ^ 1, kt2 + 1);
    const char* kbase = (const char*)pool + cur * 16384;
    __builtin_amdgcn_s_setprio(1);
#pragma unroll
    for (int cb = 0; cb < 8; ++cb) {
      int row = cb * 16 + colLane;
      const char* kb = kbase + row * 128;
      int sw = (row & 7) << 4;
      bf16x8 k0 = *(const bf16x8*)(kb + (grp16 ^ sw));
      bf16x8 k1 = *(const bf16x8*)(kb + ((64 + grp16) ^ sw));
      f32x4 a = (f32x4){0.f, 0.f, 0.f, 0.f};
      a = __builtin_amdgcn_mfma_f32_16x16x32_bf16(k0, qa0, a, 0, 0, 0);
      a = __builtin_amdgcn_mfma_f32_16x16x32_bf16(k1, qa1, a, 0, 0, 0);
      zp += exp2f(a[0]) + exp2f(a[1]) + exp2f(a[2]) + exp2f(a[3]);
    }
    __builtin_amdgcn_s_setprio(0);
    __syncthreads();
    cur ^= 1;
  }
  zp += __shfl_xor(zp, 16);
  zp += __shfl_xor(zp, 32);
  float invZ = 1.f / zp;
  float aZ = alpha * invZ, oZ = oma * invZ;

  // ---- pass 2: recompute S, normalize+gate, write attn (f32 nt), PV ----
  auto stageK = [&](int buf, int kt) {
#pragma unroll
    for (int c = 0; c < 2; ++c) {
      int o = (wv * 2 + c) * 1024 + lane * 16;
      int srcb = o ^ (((o >> 7) & 7) << 4);
      async16((const char*)Kp + kt * 8192 + srcb,
              (char*)pool + buf * 8192 + (wv * 2 + c) * 1024);
    }
  };
  auto stageV = [&](int buf, int kt) {
#pragma unroll
    for (int c = 0; c < 2; ++c) {
      int o = (wv * 2 + c) * 1024 + lane * 16;
      int d = o >> 7;
      int kb2 = (o & 127) ^ ((d & 7) << 4);
      async16((const char*)Vtg + (size_t)d * 4096 + kt * 128 + kb2,
              (char*)pool + 16384 + buf * 8192 + (wv * 2 + c) * 1024);
    }
  };

  f32x4 oacc[4];
#pragma unroll
  for (int d = 0; d < 4; ++d) oacc[d] = (f32x4){0.f, 0.f, 0.f, 0.f};

  const int qg = q0 + wv * 16 + colLane;
  const float* Mr = Mh + (size_t)qg * 2048 + grp * 4;
  float* Ar = attnOut + ((size_t)(bh * 2048 + qg)) * 2048 + grp * 4;
  char* pb = (char*)pool + 32768 + wv * 2048 + colLane * 128;
  const int psw = (colLane & 7) << 4;

  stageK(0, 0);
  stageV(0, 0);
  __syncthreads();
  cur = 0;
  for (int kt = 0; kt < 32; ++kt) {
    if (kt < 31) { stageK(cur ^ 1, kt + 1); stageV(cur ^ 1, kt + 1); }
    // hoist M loads: latency hides under QK^T MFMA + LDS reads
    const float* Mk = Mr + kt * 64;
    float4 mreg[4];
#pragma unroll
    for (int cb = 0; cb < 4; ++cb) mreg[cb] = *(const float4*)(Mk + cb * 16);
    float sc[4][4];
    {
      const char* kbase = (const char*)pool + cur * 8192;
      __builtin_amdgcn_s_setprio(1);
#pragma unroll
      for (int cb = 0; cb < 4; ++cb) {
        int row = cb * 16 + colLane;
        const char* kb = kbase + row * 128;
        int sw = (row & 7) << 4;
        bf16x8 k0 = *(const bf16x8*)(kb + (grp16 ^ sw));
        bf16x8 k1 = *(const bf16x8*)(kb + ((64 + grp16) ^ sw));
        f32x4 a = (f32x4){0.f, 0.f, 0.f, 0.f};
        a = __builtin_amdgcn_mfma_f32_16x16x32_bf16(k0, qa0, a, 0, 0, 0);
        a = __builtin_amdgcn_mfma_f32_16x16x32_bf16(k1, qa1, a, 0, 0, 0);
#pragma unroll
        for (int r = 0; r < 4; ++r) sc[cb][r] = a[r];
      }
      __builtin_amdgcn_s_setprio(0);
    }
    float* Ak = Ar + kt * 64;
#pragma unroll
    for (int cb = 0; cb < 4; ++cb) {
      f32x4 uv;
      uv[0] = exp2f(sc[cb][0]) * fmaf(aZ, mreg[cb].x, oZ);
      uv[1] = exp2f(sc[cb][1]) * fmaf(aZ, mreg[cb].y, oZ);
      uv[2] = exp2f(sc[cb][2]) * fmaf(aZ, mreg[cb].z, oZ);
      uv[3] = exp2f(sc[cb][3]) * fmaf(aZ, mreg[cb].w, oZ);
      __builtin_nontemporal_store(uv, (f32x4*)(Ak + cb * 16));
      u32x2 pv;
      pv[0] = packbf2(uv[0], uv[1]);
      pv[1] = packbf2(uv[2], uv[3]);
      *(u32x2*)(pb + ((cb * 32 + grp * 8) ^ psw)) = pv;
    }
    // PV: A-frag = P[q=colLane][k=grp*8+j] per 32-k chunk (wave-private strip)
    bf16x8 pa0 = *(const bf16x8*)(pb + (grp16 ^ psw));
    bf16x8 pa1 = *(const bf16x8*)(pb + ((64 + grp16) ^ psw));
    const char* vbase = (const char*)pool + 16384 + cur * 8192;
    __builtin_amdgcn_s_setprio(1);
#pragma unroll
    for (int db = 0; db < 4; ++db) {
      int dcol = db * 16 + colLane;
      const char* vb = vbase + dcol * 128;
      int sw = (dcol & 7) << 4;
      bf16x8 v0 = *(const bf16x8*)(vb + (grp16 ^ sw));
      bf16x8 v1 = *(const bf16x8*)(vb + ((64 + grp16) ^ sw));
      oacc[db] = __builtin_amdgcn_mfma_f32_16x16x32_bf16(pa0, v0, oacc[db], 0, 0, 0);
      oacc[db] = __builtin_amdgcn_mfma_f32_16x16x32_bf16(pa1, v1, oacc[db], 0, 0, 0);
    }
    __builtin_amdgcn_s_setprio(0);
    __syncthreads();
    cur ^= 1;
  }

  // O -> ws (bf16, [b*2048+q, h*64+d]); C layout: row=q=grp*4+r, col=d
#pragma unroll
  for (int db = 0; db < 4; ++db) {
    int dcol = db * 16 + colLane;
#pragma unroll
    for (int r = 0; r < 4; ++r) {
      int qq = q0 + wv * 16 + grp * 4 + r;
      ws[OW_ + (size_t)(b * 2048 + qq) * 512 + h * 64 + dcol] = f2bf(oacc[db][r]);
    }
  }
}

extern "C" void kernel_launch(void* const* d_in, const int* in_sizes, int n_in,
                              void* d_out, int out_size, void* d_ws, size_t ws_size,
                              hipStream_t stream) {
  const float* Qi = (const float*)d_in[0];
  const float* Ki = (const float*)d_in[1];
  const float* Vi = (const float*)d_in[2];
  const float* M = (const float*)d_in[3];
  const float* Wq = (const float*)d_in[4];
  const float* bq = (const float*)d_in[5];
  const float* Wk = (const float*)d_in[6];
  const float* bk = (const float*)d_in[7];
  const float* Wv = (const float*)d_in[8];
  const float* bv = (const float*)d_in[9];
  const float* Wo = (const float*)d_in[10];
  const float* bo = (const float*)d_in[11];
  const float* la = (const float*)d_in[12];
  u16* ws = (u16*)d_ws;
  float* outMain = (float*)d_out;
  float* outAttn = outMain + 4194304;

  convert_w<<<dim3(128, 4), 256, 0, stream>>>(Wq, Wk, Wv, Wo, ws);
  gemm_nt<0><<<dim3(4, 64, 3), 256, 0, stream>>>(Qi, Ki, Vi, ws, bq, bk, bv, nullptr);
  attn_kernel<<<dim3(32, 32), 256, 0, stream>>>(ws, M, la, outAttn);
  gemm_nt<1><<<dim3(4, 128, 1), 256, 0, stream>>>(nullptr, nullptr, nullptr, ws, bo,
                                                  nullptr, nullptr, outMain);
}